// Round 7
// baseline (561.204 us; speedup 1.0000x reference)
//
#include <hip/hip_runtime.h>

#define DF 128   // feature dim (D_IN == H == 128)
#define EB 4096  // edges per radix block

typedef short bf16x8 __attribute__((ext_vector_type(8)));
typedef float f32x4 __attribute__((ext_vector_type(4)));
typedef _Float16 h16x4 __attribute__((ext_vector_type(4)));

// ---------- helpers ----------
__device__ __forceinline__ float4 f4_relu(float4 v) {
    v.x = fmaxf(v.x, 0.f); v.y = fmaxf(v.y, 0.f); v.z = fmaxf(v.z, 0.f); v.w = fmaxf(v.w, 0.f);
    return v;
}
__device__ __forceinline__ unsigned short f32_to_bf16_rne(float f) {
    unsigned u = __float_as_uint(f);
    unsigned r = (u + 0x7fffu + ((u >> 16) & 1u)) >> 16;
    return (unsigned short)r;
}
__device__ __forceinline__ float bf16_to_f32(unsigned short h) {
    return __uint_as_float(((unsigned)h) << 16);
}
__device__ __forceinline__ void split8(float4 a, float4 b, bf16x8& hi, bf16x8& lo) {
    float v[8] = {a.x, a.y, a.z, a.w, b.x, b.y, b.z, b.w};
    #pragma unroll
    for (int j = 0; j < 8; ++j) {
        unsigned short h = f32_to_bf16_rne(v[j]);
        hi[j] = (short)h;
        float rem = v[j] - bf16_to_f32(h);
        lo[j] = (short)f32_to_bf16_rne(rem);
    }
}

// ---------- radix CSR build (all atomics in LDS) ----------
__global__ __launch_bounds__(256) void p1a_hist(const int* __restrict__ ei, int E,
                                                int NBUKP, int* __restrict__ parthist) {
    __shared__ int hist[512];
    int t = threadIdx.x;
    for (int i = t; i < NBUKP; i += 256) hist[i] = 0;
    __syncthreads();
    int e0 = blockIdx.x * EB;
    #pragma unroll
    for (int j = 0; j < EB / 256; ++j) {
        int e = e0 + j * 256 + t;
        if (e < E) atomicAdd(&hist[ei[E + e] >> 8], 1);
    }
    __syncthreads();
    for (int i = t; i < NBUKP; i += 256)
        parthist[(size_t)blockIdx.x * NBUKP + i] = hist[i];
}

__global__ __launch_bounds__(256) void colscan_kernel(int* __restrict__ parthist,
                                                      int NBLK, int NBUKP,
                                                      int* __restrict__ btotal) {
    __shared__ int wsum[4];
    int k = blockIdx.x;
    int t = threadIdx.x;
    int Q = (NBLK + 255) / 256;
    int b0 = t * Q;
    int local[8];
    int s = 0;
    for (int j = 0; j < Q; ++j) {
        int b = b0 + j;
        int v = (b < NBLK) ? parthist[(size_t)b * NBUKP + k] : 0;
        local[j] = v;
        s += v;
    }
    int lane = t & 63, wid = t >> 6;
    int incl = s;
    #pragma unroll
    for (int off = 1; off < 64; off <<= 1) {
        int n = __shfl_up(incl, off, 64);
        if (lane >= off) incl += n;
    }
    if (lane == 63) wsum[wid] = incl;
    __syncthreads();
    int wbase = 0, total = 0;
    #pragma unroll
    for (int w = 0; w < 4; ++w) {
        int v = wsum[w];
        if (w < wid) wbase += v;
        total += v;
    }
    int run = wbase + incl - s;
    for (int j = 0; j < Q; ++j) {
        int b = b0 + j;
        if (b < NBLK) parthist[(size_t)b * NBUKP + k] = run;
        run += local[j];
    }
    if (t == 0) btotal[k] = total;
}

__global__ __launch_bounds__(1024) void scan_offsets_kernel(int* __restrict__ partials, int NB,
                                                            int* __restrict__ scan_end) {
    __shared__ int wtot[16];
    int t = threadIdx.x, lane = t & 63, wid = t >> 6;
    int c = (t < NB) ? partials[t] : 0;
    int incl = c;
    #pragma unroll
    for (int off = 1; off < 64; off <<= 1) {
        int n = __shfl_up(incl, off, 64);
        if (lane >= off) incl += n;
    }
    if (lane == 63) wtot[wid] = incl;
    __syncthreads();
    int wbase = 0, total = 0;
    #pragma unroll
    for (int w = 0; w < 16; ++w) {
        int v = wtot[w];
        if (w < wid) wbase += v;
        total += v;
    }
    if (t < NB) partials[t] = wbase + incl - c;
    if (t == 0) *scan_end = total;
}

__global__ __launch_bounds__(256) void p1c_scatter(const int* __restrict__ ei, int E,
                                                   int NBUK, int NBUKP,
                                                   const int* __restrict__ parthist,
                                                   const int* __restrict__ bbase,
                                                   unsigned int* __restrict__ pbuf) {
    __shared__ int cur[512];
    int t = threadIdx.x;
    for (int i = t; i < NBUK; i += 256)
        cur[i] = bbase[i] + parthist[(size_t)blockIdx.x * NBUKP + i];
    __syncthreads();
    int e0 = blockIdx.x * EB;
    #pragma unroll
    for (int j = 0; j < EB / 256; ++j) {
        int e = e0 + j * 256 + t;
        if (e < E) {
            int s = ei[e], d = ei[E + e];
            int pos = atomicAdd(&cur[d >> 8], 1);
            pbuf[pos] = ((unsigned)s << 8) | (unsigned)(d & 255);
        }
    }
}

__global__ __launch_bounds__(256) void p2_csr(const unsigned int* __restrict__ pbuf,
                                              const int* __restrict__ bbase,
                                              int N, int E,
                                              int* __restrict__ edges4,
                                              int* __restrict__ row_start,
                                              float* __restrict__ dis) {
    __shared__ int hist[256];
    __shared__ int cur[256];
    __shared__ int wsum[4];
    int k = blockIdx.x, t = threadIdx.x;
    int gbase = bbase[k], gend = bbase[k + 1];
    hist[t] = 0;
    __syncthreads();
    for (int p = gbase + t; p < gend; p += 256)
        atomicAdd(&hist[pbuf[p] & 255], 1);
    __syncthreads();
    int c = hist[t];
    int lane = t & 63, wid = t >> 6;
    int incl = c;
    #pragma unroll
    for (int off = 1; off < 64; off <<= 1) {
        int n = __shfl_up(incl, off, 64);
        if (lane >= off) incl += n;
    }
    if (lane == 63) wsum[wid] = incl;
    __syncthreads();
    int wbase = 0;
    #pragma unroll
    for (int w = 0; w < 4; ++w)
        if (w < wid) wbase += wsum[w];
    int excl = wbase + incl - c;
    int id = k * 256 + t;
    if (id < N) {
        row_start[id] = gbase + excl;
        dis[id] = rsqrtf((float)(c + 1));   // +1 self loop
    }
    if (k == 0 && t == 0) row_start[N] = E;
    cur[t] = gbase + excl;
    __syncthreads();
    for (int p = gbase + t; p < gend; p += 256) {
        unsigned rec = pbuf[p];
        int pos = atomicAdd(&cur[rec & 255], 1);
        edges4[pos] = (int)(rec >> 8);
    }
}

// ---------- W fragment prep ----------
__global__ __launch_bounds__(256) void wprep_kernel(const float* __restrict__ Ws,
                                                    unsigned short* __restrict__ WHg,
                                                    unsigned short* __restrict__ WLg,
                                                    int total) {
    int g = blockIdx.x * 256 + threadIdx.x;
    if (g >= total) return;
    int l = g >> 11;
    int t = g & 2047;
    int s = t >> 9;
    int n = (t >> 6) & 7;
    int lane = t & 63;
    int kb = s * 32 + ((lane >> 4) << 2);
    int c  = n * 16 + (lane & 15);
    const float* W = Ws + (size_t)l * DF * DF;
    bf16x8 hi, lo;
    #pragma unroll
    for (int j = 0; j < 8; ++j) {
        int k = kb + (j & 3) + ((j >> 2) << 4);
        float w = W[k * DF + c];
        unsigned short h = f32_to_bf16_rne(w);
        hi[j] = (short)h;
        lo[j] = (short)f32_to_bf16_rne(w - bf16_to_f32(h));
    }
    *(bf16x8*)&WHg[(size_t)g * 8] = hi;
    *(bf16x8*)&WLg[(size_t)g * 8] = lo;
}

// ---------- MFMA split-bf16 GEMM, epilogue writes g = h*dis into 8 slice planes ----------
// Slice plane s holds feats [s*16, s*16+16) for all nodes: gs[s*N*16 + r*16 + f] (fp16).
// MFMA col = n*16 + l15  ->  slice s == n, f == l15.
#define GBM 128
__global__ __launch_bounds__(256) void gemm_mfma(const float* __restrict__ A,
                                                 const unsigned short* __restrict__ WHg,
                                                 const unsigned short* __restrict__ WLg,
                                                 const float* __restrict__ dis,
                                                 _Float16* __restrict__ gs,
                                                 int M, int relu) {
    int tid  = threadIdx.x;
    int wid  = tid >> 6;
    int lane = tid & 63;
    int l15  = lane & 15;
    int l4   = lane >> 4;
    size_t row0 = (size_t)blockIdx.x * GBM + wid * 32;

    f32x4 acc[2][8];
    #pragma unroll
    for (int tr = 0; tr < 2; ++tr)
        #pragma unroll
        for (int n = 0; n < 8; ++n) acc[tr][n] = (f32x4)(0.f);

    const float* Ar0 = A + (row0 + l15) * DF;
    const float* Ar1 = A + (row0 + 16 + l15) * DF;
    bool ok0 = (row0 + l15) < (size_t)M;
    bool ok1 = (row0 + 16 + l15) < (size_t)M;
    float4 zero = make_float4(0.f, 0.f, 0.f, 0.f);

    #pragma unroll
    for (int s = 0; s < 4; ++s) {
        int c0 = s * 32 + l4 * 4;
        float4 a00 = ok0 ? *(const float4*)&Ar0[c0]      : zero;
        float4 a01 = ok0 ? *(const float4*)&Ar0[c0 + 16] : zero;
        float4 a10 = ok1 ? *(const float4*)&Ar1[c0]      : zero;
        float4 a11 = ok1 ? *(const float4*)&Ar1[c0 + 16] : zero;
        if (relu) {
            a00 = f4_relu(a00); a01 = f4_relu(a01);
            a10 = f4_relu(a10); a11 = f4_relu(a11);
        }
        bf16x8 ah0, al0, ah1, al1;
        split8(a00, a01, ah0, al0);
        split8(a10, a11, ah1, al1);
        #pragma unroll
        for (int n = 0; n < 8; ++n) {
            size_t g = (size_t)((s * 8 + n) * 64 + lane) * 8;
            bf16x8 bh = *(const bf16x8*)&WHg[g];
            bf16x8 bl = *(const bf16x8*)&WLg[g];
            acc[0][n] = __builtin_amdgcn_mfma_f32_16x16x32_bf16(ah0, bh, acc[0][n], 0, 0, 0);
            acc[0][n] = __builtin_amdgcn_mfma_f32_16x16x32_bf16(ah0, bl, acc[0][n], 0, 0, 0);
            acc[0][n] = __builtin_amdgcn_mfma_f32_16x16x32_bf16(al0, bh, acc[0][n], 0, 0, 0);
            acc[1][n] = __builtin_amdgcn_mfma_f32_16x16x32_bf16(ah1, bh, acc[1][n], 0, 0, 0);
            acc[1][n] = __builtin_amdgcn_mfma_f32_16x16x32_bf16(ah1, bl, acc[1][n], 0, 0, 0);
            acc[1][n] = __builtin_amdgcn_mfma_f32_16x16x32_bf16(al1, bh, acc[1][n], 0, 0, 0);
        }
    }

    size_t plane = (size_t)M * 16;
    #pragma unroll
    for (int tr = 0; tr < 2; ++tr) {
        size_t rbase = row0 + tr * 16 + l4 * 4;
        #pragma unroll
        for (int q = 0; q < 4; ++q) {
            size_t r = rbase + q;
            if (r < (size_t)M) {
                float ds = dis[r];
                #pragma unroll
                for (int n = 0; n < 8; ++n)
                    gs[(size_t)n * plane + r * 16 + l15] = (_Float16)(acc[tr][n][q] * ds);
            }
        }
    }
}

// ---------- XCD-sliced aggregation ----------
// Block (slice s = bid&7, chunk = bid>>3) computes feats [s*16,s*16+16) for 64 nodes.
// 4 lanes/node, h16x4 (8 B) loads; per-XCD gather working set = one 3.2 MB plane (L2-fit).
// out[i][s*16+f] = dis[i]*(g[i]+sum_e g[src_e]) + bias  (fp32 full-row layout)
__global__ __launch_bounds__(256) void agg_slice(const _Float16* __restrict__ gs,
                                                 const int* __restrict__ edges4,
                                                 const int* __restrict__ row_start,
                                                 const float* __restrict__ dis,
                                                 const float* __restrict__ bias,
                                                 float* __restrict__ outB, int N) {
    int bid = blockIdx.x;
    int s   = bid & 7;
    int gid = (bid >> 3) * 64 + (threadIdx.x >> 2);
    int fl  = threadIdx.x & 3;                       // 4-feat group within slice
    if (gid >= N) return;
    const h16x4* gv = (const h16x4*)gs + (size_t)s * N * 4;
    float acc[4];
    {
        h16x4 self = gv[(size_t)gid * 4 + fl];
        #pragma unroll
        for (int j = 0; j < 4; ++j) acc[j] = (float)self[j];
    }
    int e0 = row_start[gid], e1 = row_start[gid + 1];
    int p = e0;
    for (; p + 4 <= e1; p += 4) {
        int s0 = edges4[p];
        int s1 = edges4[p + 1];
        int s2 = edges4[p + 2];
        int s3 = edges4[p + 3];
        h16x4 v0 = gv[(size_t)s0 * 4 + fl];
        h16x4 v1 = gv[(size_t)s1 * 4 + fl];
        h16x4 v2 = gv[(size_t)s2 * 4 + fl];
        h16x4 v3 = gv[(size_t)s3 * 4 + fl];
        #pragma unroll
        for (int j = 0; j < 4; ++j)
            acc[j] += (float)v0[j] + (float)v1[j] + (float)v2[j] + (float)v3[j];
    }
    for (; p < e1; ++p) {
        h16x4 v = gv[(size_t)edges4[p] * 4 + fl];
        #pragma unroll
        for (int j = 0; j < 4; ++j) acc[j] += (float)v[j];
    }
    float d = dis[gid];
    int f0 = s * 16 + fl * 4;
    float4 o;
    o.x = acc[0] * d + bias[f0 + 0];
    o.y = acc[1] * d + bias[f0 + 1];
    o.z = acc[2] * d + bias[f0 + 2];
    o.w = acc[3] * d + bias[f0 + 3];
    *(float4*)&outB[(size_t)gid * DF + f0] = o;
}

// ---------- final projection: out[i] = relu(h[i]) . Wf + bf ----------
__global__ __launch_bounds__(256) void final_kernel(const float* __restrict__ h,
                                                    const float* __restrict__ Wf,
                                                    const float* __restrict__ bf,
                                                    float* __restrict__ out, int N) {
    int gid = blockIdx.x * 16 + (threadIdx.x >> 4);
    int l8  = threadIdx.x & 15;
    if (gid >= N) return;
    const float4* hp = (const float4*)&h[(size_t)gid * DF + l8 * 8];
    float4 a = f4_relu(hp[0]);
    float4 b = f4_relu(hp[1]);
    const float4* wp = (const float4*)&Wf[l8 * 8];
    float4 wa = wp[0], wb = wp[1];
    float pr = a.x * wa.x + a.y * wa.y + a.z * wa.z + a.w * wa.w
             + b.x * wb.x + b.y * wb.y + b.z * wb.z + b.w * wb.w;
    #pragma unroll
    for (int off = 8; off > 0; off >>= 1) pr += __shfl_xor(pr, off, 16);
    if (l8 == 0) out[gid] = pr + bf[0];
}

extern "C" void kernel_launch(void* const* d_in, const int* in_sizes, int n_in,
                              void* d_out, int out_size, void* d_ws, size_t ws_size,
                              hipStream_t stream) {
    const float* x  = (const float*)d_in[0];
    const int*   ei = (const int*)d_in[1];
    const float* Ws = (const float*)d_in[2];
    const float* bs = (const float*)d_in[3];
    const float* Wf = (const float*)d_in[4];
    const float* bf = (const float*)d_in[5];
    float* out = (float*)d_out;

    int N = in_sizes[0] / DF;
    int E = in_sizes[1] / 2;
    int L = in_sizes[2] / (DF * DF);

    int NBUK  = (N + 255) >> 8;
    int NBUKP = NBUK + 1;
    int NBLK  = (E + EB - 1) / EB;

    char* p = (char*)d_ws;
    auto alloc = [&](size_t bytes) {
        char* r = p;
        p += (bytes + 255) & ~(size_t)255;
        return r;
    };
    int*   row_start = (int*)alloc((size_t)(N + 1) * 4);
    float* dis       = (float*)alloc((size_t)N * 4);
    int*   edges4    = (int*)alloc((size_t)E * 4);
    unsigned int* pbuf = (unsigned int*)alloc((size_t)E * 4);
    int*   parthist  = (int*)alloc((size_t)NBLK * NBUKP * 4);
    int*   btotal    = (int*)alloc((size_t)(NBUK + 1) * 4);
    _Float16* bufG   = (_Float16*)alloc((size_t)N * DF * 2);  // 8 slice planes
    float* bufB      = (float*)alloc((size_t)N * DF * 4);     // fp32 agg output
    unsigned short* WHg = (unsigned short*)alloc((size_t)L * 2048 * 8 * 2);
    unsigned short* WLg = (unsigned short*)alloc((size_t)L * 2048 * 8 * 2);

    int WT = L * 2048;

    wprep_kernel<<<(WT + 255) / 256, 256, 0, stream>>>(Ws, WHg, WLg, WT);
    p1a_hist<<<NBLK, 256, 0, stream>>>(ei, E, NBUKP, parthist);
    colscan_kernel<<<NBUK, 256, 0, stream>>>(parthist, NBLK, NBUKP, btotal);
    scan_offsets_kernel<<<1, 1024, 0, stream>>>(btotal, NBUK, &btotal[NBUK]);
    p1c_scatter<<<NBLK, 256, 0, stream>>>(ei, E, NBUK, NBUKP, parthist, btotal, pbuf);
    p2_csr<<<NBUK, 256, 0, stream>>>(pbuf, btotal, N, E, edges4, row_start, dis);

    int agg_grid = ((N + 63) / 64) * 8;
    const float* hin = x;
    for (int l = 0; l < L; ++l) {
        gemm_mfma<<<(N + GBM - 1) / GBM, 256, 0, stream>>>(
            hin, WHg + (size_t)l * 16384, WLg + (size_t)l * 16384, dis, bufG, N, l > 0);
        agg_slice<<<agg_grid, 256, 0, stream>>>(bufG, edges4, row_start, dis,
                                                bs + (size_t)l * DF, bufB, N);
        hin = bufB;
    }
    final_kernel<<<(N + 15) / 16, 256, 0, stream>>>(bufB, Wf, bf, out, N);
}

// Round 8
// 438.891 us; speedup vs baseline: 1.2787x; 1.2787x over previous
//
#include <hip/hip_runtime.h>

#define DF 128   // feature dim (D_IN == H == 128)
#define EB 4096  // edges per radix block

typedef short bf16x8 __attribute__((ext_vector_type(8)));
typedef float f32x4 __attribute__((ext_vector_type(4)));
typedef _Float16 h16x8 __attribute__((ext_vector_type(8)));

// ---------- helpers ----------
__device__ __forceinline__ unsigned short f32_to_bf16_rne(float f) {
    unsigned u = __float_as_uint(f);
    unsigned r = (u + 0x7fffu + ((u >> 16) & 1u)) >> 16;
    return (unsigned short)r;
}
__device__ __forceinline__ float bf16_to_f32(unsigned short h) {
    return __uint_as_float(((unsigned)h) << 16);
}
// split 8 fp16 into hi/lo bf16 fragments
__device__ __forceinline__ void split8h(h16x8 a, bf16x8& hi, bf16x8& lo) {
    #pragma unroll
    for (int j = 0; j < 8; ++j) {
        float v = (float)a[j];
        unsigned short h = f32_to_bf16_rne(v);
        hi[j] = (short)h;
        lo[j] = (short)f32_to_bf16_rne(v - bf16_to_f32(h));
    }
}

// ---------- radix CSR build (all atomics in LDS) ----------
__global__ __launch_bounds__(256) void p1a_hist(const int* __restrict__ ei, int E,
                                                int NBUKP, int* __restrict__ parthist) {
    __shared__ int hist[512];
    int t = threadIdx.x;
    for (int i = t; i < NBUKP; i += 256) hist[i] = 0;
    __syncthreads();
    int e0 = blockIdx.x * EB;
    #pragma unroll
    for (int j = 0; j < EB / 256; ++j) {
        int e = e0 + j * 256 + t;
        if (e < E) atomicAdd(&hist[ei[E + e] >> 8], 1);
    }
    __syncthreads();
    for (int i = t; i < NBUKP; i += 256)
        parthist[(size_t)blockIdx.x * NBUKP + i] = hist[i];
}

__global__ __launch_bounds__(256) void colscan_kernel(int* __restrict__ parthist,
                                                      int NBLK, int NBUKP,
                                                      int* __restrict__ btotal) {
    __shared__ int wsum[4];
    int k = blockIdx.x;
    int t = threadIdx.x;
    int Q = (NBLK + 255) / 256;
    int b0 = t * Q;
    int local[8];
    int s = 0;
    for (int j = 0; j < Q; ++j) {
        int b = b0 + j;
        int v = (b < NBLK) ? parthist[(size_t)b * NBUKP + k] : 0;
        local[j] = v;
        s += v;
    }
    int lane = t & 63, wid = t >> 6;
    int incl = s;
    #pragma unroll
    for (int off = 1; off < 64; off <<= 1) {
        int n = __shfl_up(incl, off, 64);
        if (lane >= off) incl += n;
    }
    if (lane == 63) wsum[wid] = incl;
    __syncthreads();
    int wbase = 0, total = 0;
    #pragma unroll
    for (int w = 0; w < 4; ++w) {
        int v = wsum[w];
        if (w < wid) wbase += v;
        total += v;
    }
    int run = wbase + incl - s;
    for (int j = 0; j < Q; ++j) {
        int b = b0 + j;
        if (b < NBLK) parthist[(size_t)b * NBUKP + k] = run;
        run += local[j];
    }
    if (t == 0) btotal[k] = total;
}

__global__ __launch_bounds__(1024) void scan_offsets_kernel(int* __restrict__ partials, int NB,
                                                            int* __restrict__ scan_end) {
    __shared__ int wtot[16];
    int t = threadIdx.x, lane = t & 63, wid = t >> 6;
    int c = (t < NB) ? partials[t] : 0;
    int incl = c;
    #pragma unroll
    for (int off = 1; off < 64; off <<= 1) {
        int n = __shfl_up(incl, off, 64);
        if (lane >= off) incl += n;
    }
    if (lane == 63) wtot[wid] = incl;
    __syncthreads();
    int wbase = 0, total = 0;
    #pragma unroll
    for (int w = 0; w < 16; ++w) {
        int v = wtot[w];
        if (w < wid) wbase += v;
        total += v;
    }
    if (t < NB) partials[t] = wbase + incl - c;
    if (t == 0) *scan_end = total;
}

__global__ __launch_bounds__(256) void p1c_scatter(const int* __restrict__ ei, int E,
                                                   int NBUK, int NBUKP,
                                                   const int* __restrict__ parthist,
                                                   const int* __restrict__ bbase,
                                                   unsigned int* __restrict__ pbuf) {
    __shared__ int cur[512];
    int t = threadIdx.x;
    for (int i = t; i < NBUK; i += 256)
        cur[i] = bbase[i] + parthist[(size_t)blockIdx.x * NBUKP + i];
    __syncthreads();
    int e0 = blockIdx.x * EB;
    #pragma unroll
    for (int j = 0; j < EB / 256; ++j) {
        int e = e0 + j * 256 + t;
        if (e < E) {
            int s = ei[e], d = ei[E + e];
            int pos = atomicAdd(&cur[d >> 8], 1);
            pbuf[pos] = ((unsigned)s << 8) | (unsigned)(d & 255);
        }
    }
}

__global__ __launch_bounds__(256) void p2_csr(const unsigned int* __restrict__ pbuf,
                                              const int* __restrict__ bbase,
                                              int N, int E,
                                              int* __restrict__ edges4,
                                              int* __restrict__ row_start,
                                              float* __restrict__ dis) {
    __shared__ int hist[256];
    __shared__ int cur[256];
    __shared__ int wsum[4];
    int k = blockIdx.x, t = threadIdx.x;
    int gbase = bbase[k], gend = bbase[k + 1];
    hist[t] = 0;
    __syncthreads();
    for (int p = gbase + t; p < gend; p += 256)
        atomicAdd(&hist[pbuf[p] & 255], 1);
    __syncthreads();
    int c = hist[t];
    int lane = t & 63, wid = t >> 6;
    int incl = c;
    #pragma unroll
    for (int off = 1; off < 64; off <<= 1) {
        int n = __shfl_up(incl, off, 64);
        if (lane >= off) incl += n;
    }
    if (lane == 63) wsum[wid] = incl;
    __syncthreads();
    int wbase = 0;
    #pragma unroll
    for (int w = 0; w < 4; ++w)
        if (w < wid) wbase += wsum[w];
    int excl = wbase + incl - c;
    int id = k * 256 + t;
    if (id < N) {
        row_start[id] = gbase + excl;
        dis[id] = rsqrtf((float)(c + 1));   // +1 self loop
    }
    if (k == 0 && t == 0) row_start[N] = E;
    cur[t] = gbase + excl;
    __syncthreads();
    for (int p = gbase + t; p < gend; p += 256) {
        unsigned rec = pbuf[p];
        int pos = atomicAdd(&cur[rec & 255], 1);
        edges4[pos] = (int)(rec >> 8);
    }
}

// ---------- x -> fp16 ----------
__global__ __launch_bounds__(256) void x16_kernel(const float* __restrict__ x,
                                                  _Float16* __restrict__ x16, size_t total8) {
    size_t i = (size_t)blockIdx.x * 256 + threadIdx.x;
    if (i >= total8) return;
    const float4* xp = (const float4*)&x[i * 8];
    float4 a = xp[0], b = xp[1];
    h16x8 o;
    o[0] = (_Float16)a.x; o[1] = (_Float16)a.y; o[2] = (_Float16)a.z; o[3] = (_Float16)a.w;
    o[4] = (_Float16)b.x; o[5] = (_Float16)b.y; o[6] = (_Float16)b.z; o[7] = (_Float16)b.w;
    *(h16x8*)&x16[i * 8] = o;
}

// ---------- W fragment prep (K-permuted: slot j at lane-group l4 holds k = s*32 + 8*l4 + j) ----------
__global__ __launch_bounds__(256) void wprep_kernel(const float* __restrict__ Ws,
                                                    unsigned short* __restrict__ WHg,
                                                    unsigned short* __restrict__ WLg,
                                                    int total) {
    int g = blockIdx.x * 256 + threadIdx.x;
    if (g >= total) return;
    int l = g >> 11;
    int t = g & 2047;
    int s = t >> 9;
    int n = (t >> 6) & 7;
    int lane = t & 63;
    int kb = s * 32 + ((lane >> 4) << 3);
    int c  = n * 16 + (lane & 15);
    const float* W = Ws + (size_t)l * DF * DF;
    bf16x8 hi, lo;
    #pragma unroll
    for (int j = 0; j < 8; ++j) {
        int k = kb + j;
        float w = W[k * DF + c];
        unsigned short h = f32_to_bf16_rne(w);
        hi[j] = (short)h;
        lo[j] = (short)f32_to_bf16_rne(w - bf16_to_f32(h));
    }
    *(bf16x8*)&WHg[(size_t)g * 8] = hi;
    *(bf16x8*)&WLg[(size_t)g * 8] = lo;
}

// ---------- MFMA split-bf16 GEMM: g_fp16[r] = (A16 @ W)[r] * dis[r] ----------
// A16 is fp16; each lane's A fragment is one contiguous h16x8 (K-permuted to match wprep).
#define GBM 128
__global__ __launch_bounds__(256) void gemm_mfma(const _Float16* __restrict__ A,
                                                 const unsigned short* __restrict__ WHg,
                                                 const unsigned short* __restrict__ WLg,
                                                 const float* __restrict__ dis,
                                                 _Float16* __restrict__ C,
                                                 int M) {
    int tid  = threadIdx.x;
    int wid  = tid >> 6;
    int lane = tid & 63;
    int l15  = lane & 15;
    int l4   = lane >> 4;
    size_t row0 = (size_t)blockIdx.x * GBM + wid * 32;

    f32x4 acc[2][8];
    #pragma unroll
    for (int tr = 0; tr < 2; ++tr)
        #pragma unroll
        for (int n = 0; n < 8; ++n) acc[tr][n] = (f32x4)(0.f);

    const _Float16* Ar0 = A + (row0 + l15) * DF;
    const _Float16* Ar1 = A + (row0 + 16 + l15) * DF;
    bool ok0 = (row0 + l15) < (size_t)M;
    bool ok1 = (row0 + 16 + l15) < (size_t)M;

    #pragma unroll
    for (int s = 0; s < 4; ++s) {
        int c0 = s * 32 + l4 * 8;
        h16x8 a0 = ok0 ? *(const h16x8*)&Ar0[c0] : (h16x8)(_Float16)0;
        h16x8 a1 = ok1 ? *(const h16x8*)&Ar1[c0] : (h16x8)(_Float16)0;
        bf16x8 ah0, al0, ah1, al1;
        split8h(a0, ah0, al0);
        split8h(a1, ah1, al1);
        #pragma unroll
        for (int n = 0; n < 8; ++n) {
            size_t g = (size_t)((s * 8 + n) * 64 + lane) * 8;
            bf16x8 bh = *(const bf16x8*)&WHg[g];
            bf16x8 bl = *(const bf16x8*)&WLg[g];
            acc[0][n] = __builtin_amdgcn_mfma_f32_16x16x32_bf16(ah0, bh, acc[0][n], 0, 0, 0);
            acc[0][n] = __builtin_amdgcn_mfma_f32_16x16x32_bf16(ah0, bl, acc[0][n], 0, 0, 0);
            acc[0][n] = __builtin_amdgcn_mfma_f32_16x16x32_bf16(al0, bh, acc[0][n], 0, 0, 0);
            acc[1][n] = __builtin_amdgcn_mfma_f32_16x16x32_bf16(ah1, bh, acc[1][n], 0, 0, 0);
            acc[1][n] = __builtin_amdgcn_mfma_f32_16x16x32_bf16(ah1, bl, acc[1][n], 0, 0, 0);
            acc[1][n] = __builtin_amdgcn_mfma_f32_16x16x32_bf16(al1, bh, acc[1][n], 0, 0, 0);
        }
    }

    // C/D layout: col = n*16 + l15, row = tr*16 + l4*4 + q
    #pragma unroll
    for (int tr = 0; tr < 2; ++tr) {
        size_t rbase = row0 + tr * 16 + l4 * 4;
        #pragma unroll
        for (int q = 0; q < 4; ++q) {
            size_t r = rbase + q;
            if (r < (size_t)M) {
                float ds = dis[r];
                #pragma unroll
                for (int n = 0; n < 8; ++n)
                    C[r * DF + n * 16 + l15] = (_Float16)(acc[tr][n][q] * ds);
            }
        }
    }
}

// ---------- aggregation: acc = g[i] + sum_e g[src_e]; out = dis*acc + b ----------
// FINAL=0: out fp16 row = fp16(relu(dis*acc + b))  (next layer's GEMM input)
// FINAL=1: out scalar = relu(dis*acc + b) . Wf + bf
template <int FINAL>
__global__ __launch_bounds__(256) void agg_kernel(const _Float16* __restrict__ g,
                                                  const int* __restrict__ edges4,
                                                  const int* __restrict__ row_start,
                                                  const float* __restrict__ dis,
                                                  const float* __restrict__ bias,
                                                  const float* __restrict__ Wf,
                                                  const float* __restrict__ bf,
                                                  void* __restrict__ out, int N) {
    int gid = blockIdx.x * 16 + (threadIdx.x >> 4);  // node
    int l8  = threadIdx.x & 15;                      // 8-feature slot
    if (gid >= N) return;
    const h16x8* gv = (const h16x8*)g;               // 16 per row
    float acc[8];
    {
        h16x8 self = gv[(size_t)gid * 16 + l8];
        #pragma unroll
        for (int j = 0; j < 8; ++j) acc[j] = (float)self[j];
    }
    int s = row_start[gid], e = row_start[gid + 1];
    int p = s;
    for (; p + 4 <= e; p += 4) {
        int s0 = __builtin_nontemporal_load(&edges4[p]);
        int s1 = __builtin_nontemporal_load(&edges4[p + 1]);
        int s2 = __builtin_nontemporal_load(&edges4[p + 2]);
        int s3 = __builtin_nontemporal_load(&edges4[p + 3]);
        h16x8 v0 = gv[(size_t)s0 * 16 + l8];
        h16x8 v1 = gv[(size_t)s1 * 16 + l8];
        h16x8 v2 = gv[(size_t)s2 * 16 + l8];
        h16x8 v3 = gv[(size_t)s3 * 16 + l8];
        #pragma unroll
        for (int j = 0; j < 8; ++j)
            acc[j] += (float)v0[j] + (float)v1[j] + (float)v2[j] + (float)v3[j];
    }
    for (; p < e; ++p) {
        int s0 = __builtin_nontemporal_load(&edges4[p]);
        h16x8 v = gv[(size_t)s0 * 16 + l8];
        #pragma unroll
        for (int j = 0; j < 8; ++j) acc[j] += (float)v[j];
    }
    float d = dis[gid];
    if (FINAL) {
        float pr = 0.f;
        #pragma unroll
        for (int j = 0; j < 8; ++j) {
            float v = fmaxf(acc[j] * d + bias[l8 * 8 + j], 0.f);
            pr += v * Wf[l8 * 8 + j];
        }
        #pragma unroll
        for (int off = 8; off > 0; off >>= 1) pr += __shfl_xor(pr, off, 16);
        if (l8 == 0) ((float*)out)[gid] = pr + bf[0];
    } else {
        h16x8 o;
        #pragma unroll
        for (int j = 0; j < 8; ++j)
            o[j] = (_Float16)fmaxf(acc[j] * d + bias[l8 * 8 + j], 0.f);
        *(h16x8*)&((_Float16*)out)[(size_t)gid * DF + l8 * 8] = o;
    }
}

extern "C" void kernel_launch(void* const* d_in, const int* in_sizes, int n_in,
                              void* d_out, int out_size, void* d_ws, size_t ws_size,
                              hipStream_t stream) {
    const float* x  = (const float*)d_in[0];
    const int*   ei = (const int*)d_in[1];
    const float* Ws = (const float*)d_in[2];
    const float* bs = (const float*)d_in[3];
    const float* Wf = (const float*)d_in[4];
    const float* bf = (const float*)d_in[5];
    float* out = (float*)d_out;

    int N = in_sizes[0] / DF;
    int E = in_sizes[1] / 2;
    int L = in_sizes[2] / (DF * DF);

    int NBUK  = (N + 255) >> 8;
    int NBUKP = NBUK + 1;
    int NBLK  = (E + EB - 1) / EB;

    char* p = (char*)d_ws;
    auto alloc = [&](size_t bytes) {
        char* r = p;
        p += (bytes + 255) & ~(size_t)255;
        return r;
    };
    int*   row_start = (int*)alloc((size_t)(N + 1) * 4);
    float* dis       = (float*)alloc((size_t)N * 4);
    int*   edges4    = (int*)alloc((size_t)E * 4);
    unsigned int* pbuf = (unsigned int*)alloc((size_t)E * 4);
    int*   parthist  = (int*)alloc((size_t)NBLK * NBUKP * 4);
    int*   btotal    = (int*)alloc((size_t)(NBUK + 1) * 4);
    _Float16* bufA16 = (_Float16*)alloc((size_t)N * DF * 2);  // GEMM input (fp16)
    _Float16* bufG   = (_Float16*)alloc((size_t)N * DF * 2);  // g = h*dis (fp16)
    unsigned short* WHg = (unsigned short*)alloc((size_t)L * 2048 * 8 * 2);
    unsigned short* WLg = (unsigned short*)alloc((size_t)L * 2048 * 8 * 2);

    int WT = L * 2048;
    size_t total8 = (size_t)N * DF / 8;

    wprep_kernel<<<(WT + 255) / 256, 256, 0, stream>>>(Ws, WHg, WLg, WT);
    x16_kernel<<<(int)((total8 + 255) / 256), 256, 0, stream>>>(x, bufA16, total8);
    p1a_hist<<<NBLK, 256, 0, stream>>>(ei, E, NBUKP, parthist);
    colscan_kernel<<<NBUK, 256, 0, stream>>>(parthist, NBLK, NBUKP, btotal);
    scan_offsets_kernel<<<1, 1024, 0, stream>>>(btotal, NBUK, &btotal[NBUK]);
    p1c_scatter<<<NBLK, 256, 0, stream>>>(ei, E, NBUK, NBUKP, parthist, btotal, pbuf);
    p2_csr<<<NBUK, 256, 0, stream>>>(pbuf, btotal, N, E, edges4, row_start, dis);

    for (int l = 0; l < L; ++l) {
        gemm_mfma<<<(N + GBM - 1) / GBM, 256, 0, stream>>>(
            bufA16, WHg + (size_t)l * 16384, WLg + (size_t)l * 16384, dis, bufG, N);
        if (l == L - 1) {
            agg_kernel<1><<<(N + 15) / 16, 256, 0, stream>>>(bufG, edges4, row_start, dis,
                                                             bs + (size_t)l * DF, Wf, bf, out, N);
        } else {
            agg_kernel<0><<<(N + 15) / 16, 256, 0, stream>>>(bufG, edges4, row_start, dis,
                                                             bs + (size_t)l * DF, nullptr, nullptr,
                                                             bufA16, N);
        }
    }
}